// Round 3
// baseline (424.992 us; speedup 1.0000x reference)
//
#include <hip/hip_runtime.h>
#include <hip/hip_bf16.h>
#include <stdint.h>

#define N_TOK 8192
#define DIM   1024
#define HID   2048
#define NEXP  8
#define RB    256   // route blocks (32 tokens each)

typedef __bf16 bf16x8 __attribute__((ext_vector_type(8)));
typedef float  f32x4  __attribute__((ext_vector_type(4)));
typedef unsigned short u16x8 __attribute__((ext_vector_type(8)));
typedef unsigned short u16x4 __attribute__((ext_vector_type(4)));

__device__ __forceinline__ float bits2f(unsigned short u) {
    union { unsigned int i; float f; } c; c.i = ((unsigned int)u) << 16; return c.f;
}
__device__ __forceinline__ unsigned short f2bfbits(float f) {
    __hip_bfloat16 h = __float2bfloat16(f);
    return *(unsigned short*)&h;
}

// ---- async global->LDS, 16B per lane ----
__device__ __forceinline__ void load_lds16(const void* g, void* l) {
    __builtin_amdgcn_global_load_lds(
        (const __attribute__((address_space(1))) void*)g,
        (__attribute__((address_space(3))) void*)l,
        16, 0, 0);
}

#define VMW(Nv) asm volatile("s_waitcnt vmcnt(" #Nv ")" ::: "memory")
#define BARv()  asm volatile("s_barrier" ::: "memory")
#define LGKM0() do { asm volatile("s_waitcnt lgkmcnt(0)" ::: "memory"); \
                     __builtin_amdgcn_sched_barrier(0); } while (0)

// ======================= phase 1: route + weight transpose/convert (fused) ==========
__global__ __launch_bounds__(256) void fused_pre_k(
    const float* __restrict__ x,
    const float* __restrict__ gate,
    const float* __restrict__ w1,
    const float* __restrict__ w2,
    int* __restrict__ epack, float* __restrict__ pw,
    unsigned short* __restrict__ xb,
    int* __restrict__ H0, int* __restrict__ H1, float* __restrict__ Pblk,
    unsigned short* __restrict__ w1t, unsigned short* __restrict__ w2t)
{
    __shared__ __align__(16) union {
        struct { float gw[NEXP][16][64]; int h0[NEXP]; int h1[NEXP]; float p[NEXP]; } r;
        unsigned short tile[64][72];
    } S;
    const int tid = threadIdx.x;
    const int bx  = blockIdx.x;

    if (bx < RB) {
        if (tid < NEXP) { S.r.h0[tid] = 0; S.r.h1[tid] = 0; S.r.p[tid] = 0.f; }
        for (int idx = tid; idx < NEXP * DIM; idx += 256) {
            int e = idx >> 10, rem = idx & 1023, i = rem >> 6, l = rem & 63;
            S.r.gw[e][i][l] = gate[e * DIM + l * 16 + i];
        }
        __syncthreads();
        int w = tid >> 6, lane = tid & 63;
        float prAcc[NEXP];
        #pragma unroll
        for (int e = 0; e < NEXP; ++e) prAcc[e] = 0.f;
        for (int it = 0; it < 8; ++it) {
            int token = bx * 32 + w * 8 + it;
            const float* xr = x + (size_t)token * DIM + lane * 16;
            float xv[16];
            #pragma unroll
            for (int q = 0; q < 4; ++q) {
                float4 v = *(const float4*)(xr + q * 4);
                xv[q * 4 + 0] = v.x; xv[q * 4 + 1] = v.y; xv[q * 4 + 2] = v.z; xv[q * 4 + 3] = v.w;
            }
            {
                u16x8 o0, o1;
                #pragma unroll
                for (int i = 0; i < 8; ++i) { o0[i] = f2bfbits(xv[i]); o1[i] = f2bfbits(xv[8 + i]); }
                unsigned short* dst = xb + (size_t)token * DIM + lane * 16;
                *(u16x8*)dst = o0;
                *(u16x8*)(dst + 8) = o1;
            }
            float lg[NEXP];
            #pragma unroll
            for (int e = 0; e < NEXP; ++e) {
                float s = 0.f;
                #pragma unroll
                for (int i = 0; i < 16; ++i) s += xv[i] * S.r.gw[e][i][lane];
                lg[e] = s;
            }
            #pragma unroll
            for (int off = 32; off > 0; off >>= 1)
                #pragma unroll
                for (int e = 0; e < NEXP; ++e) lg[e] += __shfl_xor(lg[e], off);
            float mx = lg[0]; int am = 0;
            #pragma unroll
            for (int e = 1; e < NEXP; ++e) if (lg[e] > mx) { mx = lg[e]; am = e; }
            float pr[NEXP], se = 0.f;
            #pragma unroll
            for (int e = 0; e < NEXP; ++e) { pr[e] = __expf(lg[e] - mx); se += pr[e]; }
            float inv = 1.f / se;
            #pragma unroll
            for (int e = 0; e < NEXP; ++e) pr[e] *= inv;
            float m2 = -1.f; int a2 = 0;
            #pragma unroll
            for (int e = 0; e < NEXP; ++e) if (e != am && pr[e] > m2) { m2 = pr[e]; a2 = e; }
            float psum = pr[am] + m2;
            if (lane == 0) {
                epack[token] = am | (a2 << 4);
                pw[token * 2] = pr[am] / psum;
                pw[token * 2 + 1] = m2 / psum;
                atomicAdd(&S.r.h0[am], 1);
                atomicAdd(&S.r.h1[a2], 1);
                #pragma unroll
                for (int e = 0; e < NEXP; ++e) prAcc[e] += pr[e];
            }
        }
        if (lane == 0) {
            #pragma unroll
            for (int e = 0; e < NEXP; ++e) atomicAdd(&S.r.p[e], prAcc[e]);
        }
        __syncthreads();
        if (tid < NEXP) {
            H0[bx * NEXP + tid] = S.r.h0[tid];
            H1[bx * NEXP + tid] = S.r.h1[tid];
            Pblk[bx * NEXP + tid] = S.r.p[tid];
        }
        return;
    }

    int bT = bx - RB;
    const float* inp; unsigned short* outp;
    int R, C, r0, c0;
    if (bT < 4096) {
        int e = bT >> 9, rem = bT & 511;
        R = DIM; C = HID;
        inp = w1 + (size_t)e * R * C; outp = w1t + (size_t)e * R * C;
        r0 = (rem >> 5) << 6; c0 = (rem & 31) << 6;
    } else {
        int b2 = bT - 4096;
        int e = b2 >> 9, rem = b2 & 511;
        R = HID; C = DIM;
        inp = w2 + (size_t)e * R * C; outp = w2t + (size_t)e * R * C;
        r0 = (rem >> 4) << 6; c0 = (rem & 15) << 6;
    }
    {
        int r = tid >> 2, cseg = (tid & 3) * 16;
        const float* src = inp + (size_t)(r0 + r) * C + c0 + cseg;
        #pragma unroll
        for (int q = 0; q < 4; ++q) {
            float4 v = *(const float4*)(src + q * 4);
            S.tile[r][cseg + q * 4 + 0] = f2bfbits(v.x);
            S.tile[r][cseg + q * 4 + 1] = f2bfbits(v.y);
            S.tile[r][cseg + q * 4 + 2] = f2bfbits(v.z);
            S.tile[r][cseg + q * 4 + 3] = f2bfbits(v.w);
        }
    }
    __syncthreads();
    {
        int c = tid >> 2, rseg = (tid & 3) * 16;
        unsigned short* dst = outp + (size_t)(c0 + c) * R + r0 + rseg;
        #pragma unroll
        for (int h = 0; h < 2; ++h) {
            u16x8 o;
            #pragma unroll
            for (int i = 0; i < 8; ++i) o[i] = S.tile[rseg + h * 8 + i][c];
            *(u16x8*)(dst + h * 8) = o;
        }
    }
}

// ======================= phase 2: scan (1 block) =======================
__global__ __launch_bounds__(256) void scan_k(
    const int* __restrict__ H0, const int* __restrict__ H1,
    const float* __restrict__ Pblk,
    int* __restrict__ bbL, int* __restrict__ counts, int* __restrict__ basep,
    float* __restrict__ aux)
{
    __shared__ int h0S[RB * NEXP], h1S[RB * NEXP], bbS[RB * NEXP];
    __shared__ float pSh[RB * NEXP];
    __shared__ int cS[NEXP], fS[NEXP];
    __shared__ float psS[NEXP];
    int tid = threadIdx.x;
    for (int i = tid; i < RB * NEXP; i += 256) { h0S[i] = H0[i]; h1S[i] = H1[i]; pSh[i] = Pblk[i]; }
    __syncthreads();
    if (tid < NEXP) {
        int run = 0, f = 0; float p = 0.f;
        for (int b = 0; b < RB; ++b) {
            int i = b * NEXP + tid;
            bbS[i] = run;
            run += h0S[i] + h1S[i];
            f += h0S[i];
            p += pSh[i];
        }
        cS[tid] = run; fS[tid] = f; psS[tid] = p;
        counts[tid] = run;
    }
    __syncthreads();
    if (tid == 0) {
        int b = 0; float s = 0.f;
        for (int e = 0; e < NEXP; ++e) {
            basep[e] = b; b += cS[e];
            s += (fS[e] * (1.f / 8192.f)) * (psS[e] * (1.f / 8192.f));
        }
        aux[0] = 0.01f * 8.f * s;
    }
    __syncthreads();
    for (int i = tid; i < RB * NEXP; i += 256) bbL[i] = bbS[i];
}

// ======================= phase 3: scatter (ballot ranking, no atomics) ==============
__global__ __launch_bounds__(256) void scatter_k(
    const int* __restrict__ epack, const int* __restrict__ bbL,
    int* __restrict__ tok_list, int* __restrict__ code)
{
    int tid = threadIdx.x;
    int w = tid >> 6, lane = tid & 63;
    int g = blockIdx.x * 4 + w;
    int token = g * 32 + (lane >> 1);
    int ep = epack[token];
    int e = (lane & 1) ? ((ep >> 4) & 0xF) : (ep & 0xF);
    unsigned long long lower = (lane == 0) ? 0ull : ((~0ull) >> (64 - lane));
    unsigned long long mymask = 0;
    #pragma unroll
    for (int ee = 0; ee < NEXP; ++ee) {
        unsigned long long m = __ballot(e == ee);
        if (ee == e) mymask = m;
    }
    int rank = __popcll(mymask & lower);
    int slot = bbL[g * NEXP + e] + rank;
    tok_list[e * N_TOK + slot] = token;
    code[token * 2 + (lane & 1)] = (e << 13) | slot;
}

// ======================= 256x256 8-wave grouped GEMM, tile-granular pipeline ========
// Tile 256x256, BK=64, 512 thr = 8 waves (2M x 4N), per-wave C = 128x64.
// LDS 128 KB, buffer b at b*32768 ushorts: A [0,16384) linear slot=row (64 ushorts
// each), B [16384,32768) slot=col.  Chunk swizzle: position p (8 ushorts) of slot s
// holds GLOBAL k-chunk p ^ (s&7); stage pre-swizzles the per-lane global address
// (gk = (tid&7) ^ ((tid>>3)&7)); fragment ds_read_b128 uses pos (kh*4+q4)^(ml&7).
// Bank check: per wave-read, 8 lanes per 16B bank-column -> uniform, conflict-free.
// Pipeline (round-1-proven skeleton, tile-granular): stage(t+1) [8 loads]; VMW(8)
// retires ALL of tile t (in-order vmcnt: everything older than the newest burst
// retires, so interleaved junk VMEM can only over-wait, never under-wait);
// asm s_barrier (memory clobber = compiler fence); ds_read + MFMA; lgkmcnt(0);
// barrier frees buffer for the next stage. vmcnt never drains in the main loop.
template<bool GATHER, bool RELU, int KT, int NTL>
__global__ __launch_bounds__(512, 2) void moe_gemm256(
    const unsigned short* __restrict__ A,
    const unsigned short* __restrict__ B,
    unsigned short* __restrict__ O,
    const int* __restrict__ counts,
    const int* __restrict__ basep,
    const int* __restrict__ tok_list,
    const int N)
{
    constexpr int K = KT * 64;
    const int bid = blockIdx.x;
    const int e  = bid & 7;            // expert == XCD (blocks round-robin XCDs)
    const int q  = bid >> 3;
    const int m0 = (q >> NTL) * 256;
    const int n0 = (q & ((1 << NTL) - 1)) * 256;
    const int cnt = counts[e];
    if (m0 >= cnt) return;
    const int bas = basep[e];

    const int tid = threadIdx.x;
    const int wid = tid >> 6, lane = tid & 63;
    const int wr = wid >> 2, wc = wid & 3;
    const int q4 = lane >> 4, ml = lane & 15;

    __shared__ __align__(16) unsigned short lds[65536];   // 128 KB

    // ---- staging source pointers (pre-swizzled global chunk) ----
    const int u  = tid >> 3;                     // slot within 64-slot group
    const int gk = (tid & 7) ^ (u & 7);          // global k-chunk for LDS pos tid&7
    const unsigned short* aR[4];
    #pragma unroll
    for (int g = 0; g < 4; ++g) {
        int slot = m0 + g * 64 + u;
        int row;
        if (GATHER) row = (slot < cnt) ? tok_list[e * N_TOK + slot] : 0;
        else        row = bas + ((slot < cnt) ? slot : (cnt - 1));
        aR[g] = A + (size_t)row * K + gk * 8;
    }
    const unsigned short* Be = B + (size_t)e * (size_t)N * K;
    const unsigned short* bR = Be + (size_t)(n0 + u) * K + gk * 8;
    const int std_ = tid * 8;                    // per-thread LDS dest (ushorts)

    auto stage = [&](int b, int t) {             // 8 global_load_lds = one full tile
        const int bo = b * 32768;
        const int tk = t * 64;
        #pragma unroll
        for (int g = 0; g < 4; ++g)
            load_lds16(aR[g] + tk, &lds[bo + g * 4096 + std_]);
        #pragma unroll
        for (int g = 0; g < 4; ++g)
            load_lds16(bR + (size_t)g * 64 * K + tk, &lds[bo + 16384 + g * 4096 + std_]);
    };

    f32x4 acc[8][4];
    #pragma unroll
    for (int i = 0; i < 8; ++i)
        #pragma unroll
        for (int j = 0; j < 4; ++j) acc[i][j] = f32x4{0.f, 0.f, 0.f, 0.f};

    const int cswz = ml & 7;
    const int cp0 = (q4 ^ cswz) * 8;             // kh=0 read position
    const int cp1 = ((4 + q4) ^ cswz) * 8;       // kh=1 read position
    int offA[8], offB[4];
    #pragma unroll
    for (int ii = 0; ii < 8; ++ii) offA[ii] = (wr * 128 + ii * 16 + ml) * 64;
    #pragma unroll
    for (int jj = 0; jj < 4; ++jj) offB[jj] = 16384 + (wc * 64 + jj * 16 + ml) * 64;

    auto compute = [&](int b) {
        const int bo = b * 32768;
        #pragma unroll
        for (int kh = 0; kh < 2; ++kh) {
            const int cp = kh ? cp1 : cp0;
            bf16x8 bF[4];
            #pragma unroll
            for (int jj = 0; jj < 4; ++jj) bF[jj] = *(const bf16x8*)&lds[bo + offB[jj] + cp];
            #pragma unroll
            for (int ii = 0; ii < 8; ++ii) {
                bf16x8 aF = *(const bf16x8*)&lds[bo + offA[ii] + cp];
                __builtin_amdgcn_s_setprio(1);
                #pragma unroll
                for (int jj = 0; jj < 4; ++jj)
                    acc[ii][jj] = __builtin_amdgcn_mfma_f32_16x16x32_bf16(
                        aF, bF[jj], acc[ii][jj], 0, 0, 0);
                __builtin_amdgcn_s_setprio(0);
            }
        }
    };

    stage(0, 0);                                  // prologue: tile 0 in flight
    for (int t = 0; t < KT; ++t) {
        const int b = t & 1;
        if (t + 1 < KT) { stage(b ^ 1, t + 1); VMW(8); }
        else            { VMW(0); }
        BARv();
        compute(b);
        LGKM0();
        BARv();
    }

    #pragma unroll
    for (int ii = 0; ii < 8; ++ii) {
        int rbase = wr * 128 + ii * 16 + q4 * 4;
        #pragma unroll
        for (int r = 0; r < 4; ++r) {
            int slot = m0 + rbase + r;
            if (slot < cnt) {
                unsigned short* orow = O + (size_t)(bas + slot) * N + n0 + wc * 64 + ml;
                #pragma unroll
                for (int jj = 0; jj < 4; ++jj) {
                    float v = acc[ii][jj][r];
                    if (RELU) v = v > 0.f ? v : 0.f;
                    orow[jj * 16] = f2bfbits(v);
                }
            }
        }
    }
}

// ======================= combine: out[t] = p0*Y[r0] + p1*Y[r1] ===========
__global__ __launch_bounds__(256) void combine_k(
    const unsigned short* __restrict__ Y,
    const int* __restrict__ code, const float* __restrict__ pw,
    const int* __restrict__ basep,
    float* __restrict__ out)
{
    int t = blockIdx.x;
    int c0 = code[t * 2], c1 = code[t * 2 + 1];
    float p0 = pw[t * 2], p1 = pw[t * 2 + 1];
    size_t r0 = (size_t)(basep[c0 >> 13] + (c0 & 0x1FFF)) * DIM;
    size_t r1 = (size_t)(basep[c1 >> 13] + (c1 & 0x1FFF)) * DIM;
    int d = threadIdx.x * 4;
    u16x4 a = *(const u16x4*)(Y + r0 + d);
    u16x4 b = *(const u16x4*)(Y + r1 + d);
    float4 o;
    o.x = p0 * bits2f(a[0]) + p1 * bits2f(b[0]);
    o.y = p0 * bits2f(a[1]) + p1 * bits2f(b[1]);
    o.z = p0 * bits2f(a[2]) + p1 * bits2f(b[2]);
    o.w = p0 * bits2f(a[3]) + p1 * bits2f(b[3]);
    *(float4*)(out + (size_t)t * DIM + d) = o;
}

// ======================= launch =======================
extern "C" void kernel_launch(void* const* d_in, const int* in_sizes, int n_in,
                              void* d_out, int out_size, void* d_ws, size_t ws_size,
                              hipStream_t stream)
{
    const float* x    = (const float*)d_in[0];
    const float* gate = (const float*)d_in[1];
    const float* w1   = (const float*)d_in[2];
    const float* w2   = (const float*)d_in[3];
    float* out = (float*)d_out;

    char* ws = (char*)d_ws;
    int*   counts   = (int*)(ws + 0);
    int*   basep    = (int*)(ws + 256);
    int*   epack    = (int*)(ws + 1024);                      // 32 KB
    int*   H0       = (int*)(ws + 1024 + 32768);
    int*   H1       = (int*)(ws + 1024 + 40960);
    float* Pblk     = (float*)(ws + 1024 + 49152);
    int*   bbL      = (int*)(ws + 1024 + 57344);
    int*   tok_list = (int*)(ws + 131072);                    // 256 KB
    int*   code     = (int*)(ws + 131072 + 262144);           // 64 KB
    float* pw       = (float*)(ws + 131072 + 262144 + 65536); // 64 KB
    // big buffers (all bf16):
    //   [1MB, 33MB)   w1t
    //   [33MB, 65MB)  w2t
    //   [65MB,129MB)  hidden
    //   [129MB,161MB) xb (first 16MB; dead after GEMM1) -> reused as Y
    unsigned short* w1t    = (unsigned short*)(ws + (1 << 20));
    unsigned short* w2t    = (unsigned short*)(ws + (1 << 20) + 33554432);
    unsigned short* hidden = (unsigned short*)(ws + (1 << 20) + 67108864);
    unsigned short* xb     = (unsigned short*)(ws + (1 << 20) + 134217728);
    unsigned short* Y      = xb;   // GEMM2 output (xb dead by then)

    fused_pre_k<<<RB + 8192, 256, 0, stream>>>(x, gate, w1, w2, epack, pw, xb,
                                               H0, H1, Pblk, w1t, w2t);
    scan_k<<<1, 256, 0, stream>>>(H0, H1, Pblk, bbL, counts, basep, out + (size_t)N_TOK * DIM);
    scatter_k<<<64, 256, 0, stream>>>(epack, bbL, tok_list, code);
    // flat 1-D grids: expert = bid&7 pins each expert to one XCD (B-panel L2-resident)
    moe_gemm256<true, true, DIM / 64, 3><<<NEXP * 32 * 8, 512, 0, stream>>>(
        xb, w1t, hidden, counts, basep, tok_list, HID);
    moe_gemm256<false, false, HID / 64, 2><<<NEXP * 32 * 4, 512, 0, stream>>>(
        hidden, w2t, Y, counts, basep, tok_list, DIM);
    combine_k<<<N_TOK, 256, 0, stream>>>(Y, code, pw, basep, out);
}

// Round 4
// 395.453 us; speedup vs baseline: 1.0747x; 1.0747x over previous
//
#include <hip/hip_runtime.h>
#include <hip/hip_bf16.h>
#include <stdint.h>

#define N_TOK 8192
#define DIM   1024
#define HID   2048
#define NEXP  8
#define RB    256   // route blocks (32 tokens each)

typedef __bf16 bf16x8 __attribute__((ext_vector_type(8)));
typedef float  f32x4  __attribute__((ext_vector_type(4)));
typedef unsigned short u16x8 __attribute__((ext_vector_type(8)));
typedef unsigned short u16x4 __attribute__((ext_vector_type(4)));

__device__ __forceinline__ float bits2f(unsigned short u) {
    union { unsigned int i; float f; } c; c.i = ((unsigned int)u) << 16; return c.f;
}
__device__ __forceinline__ unsigned short f2bfbits(float f) {
    __hip_bfloat16 h = __float2bfloat16(f);
    return *(unsigned short*)&h;
}

// ---- async global->LDS, 16B per lane ----
__device__ __forceinline__ void load_lds16(const void* g, void* l) {
    __builtin_amdgcn_global_load_lds(
        (const __attribute__((address_space(1))) void*)g,
        (__attribute__((address_space(3))) void*)l,
        16, 0, 0);
}

#define VMW(Nv) asm volatile("s_waitcnt vmcnt(" #Nv ")" ::: "memory")
#define BARv()  asm volatile("s_barrier" ::: "memory")
#define LGKM0() do { asm volatile("s_waitcnt lgkmcnt(0)" ::: "memory"); \
                     __builtin_amdgcn_sched_barrier(0); } while (0)

// ======================= phase 1: route + weight transpose/convert (fused) ==========
__global__ __launch_bounds__(256) void fused_pre_k(
    const float* __restrict__ x,
    const float* __restrict__ gate,
    const float* __restrict__ w1,
    const float* __restrict__ w2,
    int* __restrict__ epack, float* __restrict__ pw,
    unsigned short* __restrict__ xb,
    int* __restrict__ H0, int* __restrict__ H1, float* __restrict__ Pblk,
    unsigned short* __restrict__ w1t, unsigned short* __restrict__ w2t)
{
    __shared__ __align__(16) union {
        struct { float gw[NEXP][16][64]; int h0[NEXP]; int h1[NEXP]; float p[NEXP]; } r;
        unsigned short tile[64][72];
    } S;
    const int tid = threadIdx.x;
    const int bx  = blockIdx.x;

    if (bx < RB) {
        if (tid < NEXP) { S.r.h0[tid] = 0; S.r.h1[tid] = 0; S.r.p[tid] = 0.f; }
        for (int idx = tid; idx < NEXP * DIM; idx += 256) {
            int e = idx >> 10, rem = idx & 1023, i = rem >> 6, l = rem & 63;
            S.r.gw[e][i][l] = gate[e * DIM + l * 16 + i];
        }
        __syncthreads();
        int w = tid >> 6, lane = tid & 63;
        float prAcc[NEXP];
        #pragma unroll
        for (int e = 0; e < NEXP; ++e) prAcc[e] = 0.f;
        for (int it = 0; it < 8; ++it) {
            int token = bx * 32 + w * 8 + it;
            const float* xr = x + (size_t)token * DIM + lane * 16;
            float xv[16];
            #pragma unroll
            for (int q = 0; q < 4; ++q) {
                float4 v = *(const float4*)(xr + q * 4);
                xv[q * 4 + 0] = v.x; xv[q * 4 + 1] = v.y; xv[q * 4 + 2] = v.z; xv[q * 4 + 3] = v.w;
            }
            {
                u16x8 o0, o1;
                #pragma unroll
                for (int i = 0; i < 8; ++i) { o0[i] = f2bfbits(xv[i]); o1[i] = f2bfbits(xv[8 + i]); }
                unsigned short* dst = xb + (size_t)token * DIM + lane * 16;
                *(u16x8*)dst = o0;
                *(u16x8*)(dst + 8) = o1;
            }
            float lg[NEXP];
            #pragma unroll
            for (int e = 0; e < NEXP; ++e) {
                float s = 0.f;
                #pragma unroll
                for (int i = 0; i < 16; ++i) s += xv[i] * S.r.gw[e][i][lane];
                lg[e] = s;
            }
            #pragma unroll
            for (int off = 32; off > 0; off >>= 1)
                #pragma unroll
                for (int e = 0; e < NEXP; ++e) lg[e] += __shfl_xor(lg[e], off);
            float mx = lg[0]; int am = 0;
            #pragma unroll
            for (int e = 1; e < NEXP; ++e) if (lg[e] > mx) { mx = lg[e]; am = e; }
            float pr[NEXP], se = 0.f;
            #pragma unroll
            for (int e = 0; e < NEXP; ++e) { pr[e] = __expf(lg[e] - mx); se += pr[e]; }
            float inv = 1.f / se;
            #pragma unroll
            for (int e = 0; e < NEXP; ++e) pr[e] *= inv;
            float m2 = -1.f; int a2 = 0;
            #pragma unroll
            for (int e = 0; e < NEXP; ++e) if (e != am && pr[e] > m2) { m2 = pr[e]; a2 = e; }
            float psum = pr[am] + m2;
            if (lane == 0) {
                epack[token] = am | (a2 << 4);
                pw[token * 2] = pr[am] / psum;
                pw[token * 2 + 1] = m2 / psum;
                atomicAdd(&S.r.h0[am], 1);
                atomicAdd(&S.r.h1[a2], 1);
                #pragma unroll
                for (int e = 0; e < NEXP; ++e) prAcc[e] += pr[e];
            }
        }
        if (lane == 0) {
            #pragma unroll
            for (int e = 0; e < NEXP; ++e) atomicAdd(&S.r.p[e], prAcc[e]);
        }
        __syncthreads();
        if (tid < NEXP) {
            H0[bx * NEXP + tid] = S.r.h0[tid];
            H1[bx * NEXP + tid] = S.r.h1[tid];
            Pblk[bx * NEXP + tid] = S.r.p[tid];
        }
        return;
    }

    int bT = bx - RB;
    const float* inp; unsigned short* outp;
    int R, C, r0, c0;
    if (bT < 4096) {
        int e = bT >> 9, rem = bT & 511;
        R = DIM; C = HID;
        inp = w1 + (size_t)e * R * C; outp = w1t + (size_t)e * R * C;
        r0 = (rem >> 5) << 6; c0 = (rem & 31) << 6;
    } else {
        int b2 = bT - 4096;
        int e = b2 >> 9, rem = b2 & 511;
        R = HID; C = DIM;
        inp = w2 + (size_t)e * R * C; outp = w2t + (size_t)e * R * C;
        r0 = (rem >> 4) << 6; c0 = (rem & 15) << 6;
    }
    {
        int r = tid >> 2, cseg = (tid & 3) * 16;
        const float* src = inp + (size_t)(r0 + r) * C + c0 + cseg;
        #pragma unroll
        for (int q = 0; q < 4; ++q) {
            float4 v = *(const float4*)(src + q * 4);
            S.tile[r][cseg + q * 4 + 0] = f2bfbits(v.x);
            S.tile[r][cseg + q * 4 + 1] = f2bfbits(v.y);
            S.tile[r][cseg + q * 4 + 2] = f2bfbits(v.z);
            S.tile[r][cseg + q * 4 + 3] = f2bfbits(v.w);
        }
    }
    __syncthreads();
    {
        int c = tid >> 2, rseg = (tid & 3) * 16;
        unsigned short* dst = outp + (size_t)(c0 + c) * R + r0 + rseg;
        #pragma unroll
        for (int h = 0; h < 2; ++h) {
            u16x8 o;
            #pragma unroll
            for (int i = 0; i < 8; ++i) o[i] = S.tile[rseg + h * 8 + i][c];
            *(u16x8*)(dst + h * 8) = o;
        }
    }
}

// ======================= phase 2: scan (1 block) =======================
__global__ __launch_bounds__(256) void scan_k(
    const int* __restrict__ H0, const int* __restrict__ H1,
    const float* __restrict__ Pblk,
    int* __restrict__ bbL, int* __restrict__ counts, int* __restrict__ basep,
    float* __restrict__ aux)
{
    __shared__ int h0S[RB * NEXP], h1S[RB * NEXP], bbS[RB * NEXP];
    __shared__ float pSh[RB * NEXP];
    __shared__ int cS[NEXP], fS[NEXP];
    __shared__ float psS[NEXP];
    int tid = threadIdx.x;
    for (int i = tid; i < RB * NEXP; i += 256) { h0S[i] = H0[i]; h1S[i] = H1[i]; pSh[i] = Pblk[i]; }
    __syncthreads();
    if (tid < NEXP) {
        int run = 0, f = 0; float p = 0.f;
        for (int b = 0; b < RB; ++b) {
            int i = b * NEXP + tid;
            bbS[i] = run;
            run += h0S[i] + h1S[i];
            f += h0S[i];
            p += pSh[i];
        }
        cS[tid] = run; fS[tid] = f; psS[tid] = p;
        counts[tid] = run;
    }
    __syncthreads();
    if (tid == 0) {
        int b = 0; float s = 0.f;
        for (int e = 0; e < NEXP; ++e) {
            basep[e] = b; b += cS[e];
            s += (fS[e] * (1.f / 8192.f)) * (psS[e] * (1.f / 8192.f));
        }
        aux[0] = 0.01f * 8.f * s;
    }
    __syncthreads();
    for (int i = tid; i < RB * NEXP; i += 256) bbL[i] = bbS[i];
}

// ======================= phase 3: scatter (ballot ranking, no atomics) ==============
__global__ __launch_bounds__(256) void scatter_k(
    const int* __restrict__ epack, const int* __restrict__ bbL,
    int* __restrict__ tok_list, int* __restrict__ code)
{
    int tid = threadIdx.x;
    int w = tid >> 6, lane = tid & 63;
    int g = blockIdx.x * 4 + w;
    int token = g * 32 + (lane >> 1);
    int ep = epack[token];
    int e = (lane & 1) ? ((ep >> 4) & 0xF) : (ep & 0xF);
    unsigned long long lower = (lane == 0) ? 0ull : ((~0ull) >> (64 - lane));
    unsigned long long mymask = 0;
    #pragma unroll
    for (int ee = 0; ee < NEXP; ++ee) {
        unsigned long long m = __ballot(e == ee);
        if (ee == e) mymask = m;
    }
    int rank = __popcll(mymask & lower);
    int slot = bbL[g * NEXP + e] + rank;
    tok_list[e * N_TOK + slot] = token;
    code[token * 2 + (lane & 1)] = (e << 13) | slot;
}

// ======================= 256x256 8-wave grouped GEMM, 4-phase counted-vmcnt =========
// Tile 256x256, BK=64, 512 thr = 8 waves (wr=wid>>2 in {0,1}, wc=wid&3 in 0..3).
// Per-wave C: rows {mh*128 + wr*64 + ii*16 + ml}, cols {nh*128 + wc*32 + jj*16 + ml}
// (mh,nh in {0,1}; ii 0..3; jj 0..1) -> acc[mh*4+ii][nh*2+jj].
// LDS 128 KB, buffer b at b*32768 ushorts, ALL LINEAR maps:
//   A [0,16384): row r at r*64    B [16384,32768): col c at 16384 + c*64
// Chunk swizzle (proven rounds 0-3): position p (8 ush) of slot s holds global
// k-chunk p ^ (s&7); stage pre-swizzles global addr (gk=(tid&7)^((tid>>3)&7));
// frag read position (kh*4+q4) ^ (ml&7). Conflict-free (measured 0).
// Stage groups (2 x global_load_lds each), issue order = retire order:
//   G0=A rows[0,128)  G1=B cols[0,128)  G2=B cols[128,256)  G3=A rows[128,256)
// 4 phases/tile, each = stage for t+1 -> VMW(8) -> s_barrier -> ds_read one
// contiguous region -> lgkmcnt(0)+sched_barrier -> setprio MFMA quadrant:
//   p0: +G0,G1(t+1)  read A-mh0,B-nh0  mm(0,0)     p1: +G2(t+1) read B-nh1 mm(0,1)
//   p2: +G3(t+1)     read A-mh1        mm(1,0)     p3: (regs)              mm(1,1)
// Ledger (in-order vmcnt): steady-state outstanding after each phase-issue is
// 12/10/10; VMW(8) retires exactly the group(s) the phase reads. Last tile
// drains 4 -> 2 -> 0. Overwrite windows audited: every stage targets a region
// whose last reader LGKM0'd before a barrier the stager already crossed.
template<bool GATHER, bool RELU, int KT, int NTL>
__global__ __launch_bounds__(512, 2) void moe_gemm256(
    const unsigned short* __restrict__ A,
    const unsigned short* __restrict__ B,
    unsigned short* __restrict__ O,
    const int* __restrict__ counts,
    const int* __restrict__ basep,
    const int* __restrict__ tok_list,
    const int N)
{
    constexpr int K = KT * 64;
    const int bid = blockIdx.x;
    const int e  = bid & 7;            // expert == XCD (blocks round-robin XCDs)
    const int q  = bid >> 3;
    const int m0 = (q >> NTL) * 256;
    const int n0 = (q & ((1 << NTL) - 1)) * 256;
    const int cnt = counts[e];
    if (m0 >= cnt) return;
    const int bas = basep[e];

    const int tid = threadIdx.x;
    const int wid = tid >> 6, lane = tid & 63;
    const int wr = wid >> 2, wc = wid & 3;
    const int q4 = lane >> 4, ml = lane & 15;

    __shared__ __align__(16) unsigned short lds[65536];   // 128 KB

    // ---- staging source pointers (pre-swizzled global chunk) ----
    const int u  = tid >> 3;                     // slot within 64-slot instr
    const int gk = (tid & 7) ^ (u & 7);          // global k-chunk for LDS pos tid&7
    const unsigned short* aR[4];
    #pragma unroll
    for (int g = 0; g < 4; ++g) {
        int slot = m0 + g * 64 + u;
        int row;
        if (GATHER) row = (slot < cnt) ? tok_list[e * N_TOK + slot] : 0;
        else        row = bas + ((slot < cnt) ? slot : (cnt - 1));
        aR[g] = A + (size_t)row * K + gk * 8;
    }
    const unsigned short* Be = B + (size_t)e * (size_t)N * K;
    const unsigned short* bR = Be + (size_t)(n0 + u) * K + gk * 8;
    const int std_ = tid * 8;                    // per-thread LDS dest (ushorts)

    auto gA01 = [&](int bo_, int t_) {           // G0: A rows [0,128)
        load_lds16(aR[0] + t_ * 64, &lds[bo_ + std_]);
        load_lds16(aR[1] + t_ * 64, &lds[bo_ + 4096 + std_]);
    };
    auto gB01 = [&](int bo_, int t_) {           // G1: B cols [0,128)
        load_lds16(bR + t_ * 64,                    &lds[bo_ + 16384 + std_]);
        load_lds16(bR + (size_t)64 * K + t_ * 64,   &lds[bo_ + 20480 + std_]);
    };
    auto gB23 = [&](int bo_, int t_) {           // G2: B cols [128,256)
        load_lds16(bR + (size_t)128 * K + t_ * 64,  &lds[bo_ + 24576 + std_]);
        load_lds16(bR + (size_t)192 * K + t_ * 64,  &lds[bo_ + 28672 + std_]);
    };
    auto gA23 = [&](int bo_, int t_) {           // G3: A rows [128,256)
        load_lds16(aR[2] + t_ * 64, &lds[bo_ + 8192 + std_]);
        load_lds16(aR[3] + t_ * 64, &lds[bo_ + 12288 + std_]);
    };

    f32x4 acc[8][4];
    #pragma unroll
    for (int i = 0; i < 8; ++i)
        #pragma unroll
        for (int j = 0; j < 4; ++j) acc[i][j] = f32x4{0.f, 0.f, 0.f, 0.f};

    const int cswz = ml & 7;
    const int cp0 = (q4 ^ cswz) * 8;             // kh=0 read position
    const int cp1 = ((4 + q4) ^ cswz) * 8;       // kh=1 read position
    const int aoff = (wr * 64 + ml) * 64;        // + mh*8192 + ii*1024
    const int boff = 16384 + (wc * 32 + ml) * 64;// + nh*8192 + jj*1024

    bf16x8 aF[4][2], bF[4][2];
    auto readA = [&](int bo_, int mh) {
        #pragma unroll
        for (int ii = 0; ii < 4; ++ii) {
            int o = bo_ + aoff + mh * 8192 + ii * 1024;
            aF[ii][0] = *(const bf16x8*)&lds[o + cp0];
            aF[ii][1] = *(const bf16x8*)&lds[o + cp1];
        }
    };
    auto readB = [&](int bo_, int nh) {
        #pragma unroll
        for (int jj = 0; jj < 2; ++jj) {
            int o = bo_ + boff + nh * 8192 + jj * 1024;
            bF[nh * 2 + jj][0] = *(const bf16x8*)&lds[o + cp0];
            bF[nh * 2 + jj][1] = *(const bf16x8*)&lds[o + cp1];
        }
    };
    auto mm = [&](int mh, int nh) {
        __builtin_amdgcn_s_setprio(1);
        #pragma unroll
        for (int ii = 0; ii < 4; ++ii)
            #pragma unroll
            for (int jj = 0; jj < 2; ++jj) {
                acc[mh * 4 + ii][nh * 2 + jj] = __builtin_amdgcn_mfma_f32_16x16x32_bf16(
                    aF[ii][0], bF[nh * 2 + jj][0], acc[mh * 4 + ii][nh * 2 + jj], 0, 0, 0);
                acc[mh * 4 + ii][nh * 2 + jj] = __builtin_amdgcn_mfma_f32_16x16x32_bf16(
                    aF[ii][1], bF[nh * 2 + jj][1], acc[mh * 4 + ii][nh * 2 + jj], 0, 0, 0);
            }
        __builtin_amdgcn_s_setprio(0);
    };

    // prologue: all 4 groups of tile 0 (8 loads), oldest-first
    gA01(0, 0); gB01(0, 0); gB23(0, 0); gA23(0, 0);

    for (int t = 0; t < KT - 1; ++t) {
        const int bo = (t & 1) << 15;
        const int nx = bo ^ 32768;
        // p0
        gA01(nx, t + 1); gB01(nx, t + 1);
        VMW(8); BARv();
        readA(bo, 0); readB(bo, 0);
        LGKM0();
        mm(0, 0);
        // p1
        gB23(nx, t + 1);
        VMW(8); BARv();
        readB(bo, 1);
        LGKM0();
        mm(0, 1);
        // p2
        gA23(nx, t + 1);
        VMW(8); BARv();
        readA(bo, 1);
        LGKM0();
        mm(1, 0);
        // p3 (registers only)
        mm(1, 1);
    }
    {   // last tile: drain 4 -> 2 -> 0
        const int bo = ((KT - 1) & 1) << 15;
        VMW(4); BARv(); readA(bo, 0); readB(bo, 0); LGKM0(); mm(0, 0);
        VMW(2); BARv(); readB(bo, 1);               LGKM0(); mm(0, 1);
        VMW(0); BARv(); readA(bo, 1);               LGKM0(); mm(1, 0);
        mm(1, 1);
    }

    #pragma unroll
    for (int mh = 0; mh < 2; ++mh)
        #pragma unroll
        for (int ii = 0; ii < 4; ++ii) {
            int rbase = mh * 128 + wr * 64 + ii * 16 + q4 * 4;
            #pragma unroll
            for (int r = 0; r < 4; ++r) {
                int slot = m0 + rbase + r;
                if (slot < cnt) {
                    unsigned short* orow = O + (size_t)(bas + slot) * N + n0 + wc * 32 + ml;
                    #pragma unroll
                    for (int nh = 0; nh < 2; ++nh)
                        #pragma unroll
                        for (int jj = 0; jj < 2; ++jj) {
                            float v = acc[mh * 4 + ii][nh * 2 + jj][r];
                            if (RELU) v = v > 0.f ? v : 0.f;
                            orow[nh * 128 + jj * 16] = f2bfbits(v);
                        }
                }
            }
        }
}

// ======================= combine: out[t] = p0*Y[r0] + p1*Y[r1] ===========
__global__ __launch_bounds__(256) void combine_k(
    const unsigned short* __restrict__ Y,
    const int* __restrict__ code, const float* __restrict__ pw,
    const int* __restrict__ basep,
    float* __restrict__ out)
{
    int t = blockIdx.x;
    int c0 = code[t * 2], c1 = code[t * 2 + 1];
    float p0 = pw[t * 2], p1 = pw[t * 2 + 1];
    size_t r0 = (size_t)(basep[c0 >> 13] + (c0 & 0x1FFF)) * DIM;
    size_t r1 = (size_t)(basep[c1 >> 13] + (c1 & 0x1FFF)) * DIM;
    int d = threadIdx.x * 4;
    u16x4 a = *(const u16x4*)(Y + r0 + d);
    u16x4 b = *(const u16x4*)(Y + r1 + d);
    float4 o;
    o.x = p0 * bits2f(a[0]) + p1 * bits2f(b[0]);
    o.y = p0 * bits2f(a[1]) + p1 * bits2f(b[1]);
    o.z = p0 * bits2f(a[2]) + p1 * bits2f(b[2]);
    o.w = p0 * bits2f(a[3]) + p1 * bits2f(b[3]);
    *(float4*)(out + (size_t)t * DIM + d) = o;
}

// ======================= launch =======================
extern "C" void kernel_launch(void* const* d_in, const int* in_sizes, int n_in,
                              void* d_out, int out_size, void* d_ws, size_t ws_size,
                              hipStream_t stream)
{
    const float* x    = (const float*)d_in[0];
    const float* gate = (const float*)d_in[1];
    const float* w1   = (const float*)d_in[2];
    const float* w2   = (const float*)d_in[3];
    float* out = (float*)d_out;

    char* ws = (char*)d_ws;
    int*   counts   = (int*)(ws + 0);
    int*   basep    = (int*)(ws + 256);
    int*   epack    = (int*)(ws + 1024);                      // 32 KB
    int*   H0       = (int*)(ws + 1024 + 32768);
    int*   H1       = (int*)(ws + 1024 + 40960);
    float* Pblk     = (float*)(ws + 1024 + 49152);
    int*   bbL      = (int*)(ws + 1024 + 57344);
    int*   tok_list = (int*)(ws + 131072);                    // 256 KB
    int*   code     = (int*)(ws + 131072 + 262144);           // 64 KB
    float* pw       = (float*)(ws + 131072 + 262144 + 65536); // 64 KB
    // big buffers (all bf16):
    //   [1MB, 33MB)   w1t
    //   [33MB, 65MB)  w2t
    //   [65MB,129MB)  hidden
    //   [129MB,161MB) xb (first 16MB; dead after GEMM1) -> reused as Y
    unsigned short* w1t    = (unsigned short*)(ws + (1 << 20));
    unsigned short* w2t    = (unsigned short*)(ws + (1 << 20) + 33554432);
    unsigned short* hidden = (unsigned short*)(ws + (1 << 20) + 67108864);
    unsigned short* xb     = (unsigned short*)(ws + (1 << 20) + 134217728);
    unsigned short* Y      = xb;   // GEMM2 output (xb dead by then)

    fused_pre_k<<<RB + 8192, 256, 0, stream>>>(x, gate, w1, w2, epack, pw, xb,
                                               H0, H1, Pblk, w1t, w2t);
    scan_k<<<1, 256, 0, stream>>>(H0, H1, Pblk, bbL, counts, basep, out + (size_t)N_TOK * DIM);
    scatter_k<<<64, 256, 0, stream>>>(epack, bbL, tok_list, code);
    // flat 1-D grids: expert = bid&7 pins each expert to one XCD (B-panel L2-resident)
    moe_gemm256<true, true, DIM / 64, 3><<<NEXP * 32 * 8, 512, 0, stream>>>(
        xb, w1t, hidden, counts, basep, tok_list, HID);
    moe_gemm256<false, false, HID / 64, 2><<<NEXP * 32 * 4, 512, 0, stream>>>(
        hidden, w2t, Y, counts, basep, tok_list, DIM);
    combine_k<<<N_TOK, 256, 0, stream>>>(Y, code, pw, basep, out);
}